// Round 6
// baseline (101.323 us; speedup 1.0000x reference)
//
#include <hip/hip_runtime.h>
#include <stdint.h>

// Problem dims: B=1, H=W=128, HW=16384, P=128, F=64
#define HW 16384
#define P 128
#define F 64
#define RPB 8   // rays per block, software-pipelined

// Workgroup barrier WITHOUT the vmcnt(0) drain __syncthreads emits.
// LDS ordering only (lgkmcnt). Keeps the feat gather in flight across
// the next ray's prologue. (rule #18: sched_barrier(0) fences the asm.)
#define BAR_LDS()                                            \
    do {                                                     \
        asm volatile("s_waitcnt lgkmcnt(0)" ::: "memory");   \
        __builtin_amdgcn_sched_barrier(0);                   \
        __builtin_amdgcn_s_barrier();                        \
        __builtin_amdgcn_sched_barrier(0);                   \
    } while (0)

// Full per-ray prologue: stable sort -> alpha -> cumprod scan -> weights,
// nonzero compaction -> per-thread (pj, wj) gather plan in registers.
// Only LDS barriers inside (BAR_LDS) — never drains vmcnt.
__device__ __forceinline__ void ray_prologue(
    int r, int tid, int lane, int wv, int ps,
    float myd, float mysig, float rx, float ry, float rz,
    unsigned long long* skey, float* sdep, float* ssig, int* sidx,
    float* sw, int* srank, int* plist, unsigned long long* smask,
    float* swave,
    float* __restrict__ out_weights, float* __restrict__ out_depth,
    float* __restrict__ out_alpha,
    int pj[8], float wj[8])
{
    // stable sort keys (depth in [0,1) -> float bits order-preserving)
    if (tid < P)
        skey[tid] = ((unsigned long long)__float_as_uint(myd) << 32) | (unsigned)tid;
    BAR_LDS();

    // O(P) rank sort, comparisons split across all 256 threads
    {
        const int k  = tid & (P - 1);
        const int jb = (tid >> 7) << 6;
        const unsigned long long mk = skey[k];
        int rk = 0;
        #pragma unroll 16
        for (int j = 0; j < 64; ++j)
            rk += (skey[jb + j] < mk) ? 1 : 0;
        srank[tid] = rk;
    }
    BAR_LDS();
    if (tid < P) {
        const int rank = srank[tid] + srank[tid + P];  // unique (idx tie-break)
        sdep[rank] = myd;
        ssig[rank] = mysig;
        sidx[rank] = tid;
    }
    BAR_LDS();

    // alpha at sorted position p = tid (tid < 128)
    float tp = 1.0f, alpha = 0.f, dsort = 0.f;
    if (tid < P) {
        dsort = sdep[tid];
        const float dz = (tid < P - 1) ? (sdep[tid + 1] - dsort) : 1e10f;
        const float rn = sqrtf(rx * rx + ry * ry + rz * rz);
        const float sg = fmaxf(ssig[tid], 0.0f);
        alpha = 1.0f - expf(-sg * dz * rn);
        tp = (1.0f - alpha) + 1e-10f;   // match ref expression order
    }

    // inclusive product scan via shfl (waves 0,1 carry real data)
    float scan = tp;
    #pragma unroll
    for (int off = 1; off < 64; off <<= 1) {
        const float v = __shfl_up(scan, off);
        if (lane >= off) scan *= v;
    }
    if (lane == 63 && wv < 2) swave[wv] = scan;
    BAR_LDS();

    float w = 0.f;
    int   myoff = 0;
    if (tid < P) {
        float excl = __shfl_up(scan, 1);
        if (lane == 0) excl = 1.0f;
        if (wv == 1) excl *= swave[0];
        w = alpha * excl;

        out_weights[(size_t)r * P + tid] = w;      // sorted order (output 4)
        sw[sidx[tid]] = w;                         // original order (LDS)

        const unsigned long long mask = __ballot(w != 0.0f);
        if (lane == 0) smask[wv] = mask;
        myoff = (int)__popcll(mask & ((1ull << lane) - 1ull));

        float s1 = w, s2 = w * dsort;              // w >= 0 so |w| = w
        #pragma unroll
        for (int off = 32; off > 0; off >>= 1) {
            s1 += __shfl_xor(s1, off);
            s2 += __shfl_xor(s2, off);
        }
        if (lane == 0) { swave[2 + wv * 2] = s1; swave[3 + wv * 2] = s2; }
    }
    BAR_LDS();   // sw + swave + smask ready

    const int M = (int)(__popcll(smask[0]) + __popcll(smask[1]));
    if (tid < P && w != 0.0f) {
        const int rank = myoff + ((wv == 1) ? (int)__popcll(smask[0]) : 0);
        plist[rank] = sidx[tid];                   // compacted original indices
    }
    if (tid == 0) {
        const float sumw  = swave[2] + swave[4];
        const float sumwd = swave[3] + swave[5];
        float dm = sumwd / fmaxf(sumw, 1e-12f);
        dm = (dm - 0.001f) / (1000.0f - 0.001f);
        dm = fminf(fmaxf(dm, 0.0f), 1.0f);
        out_depth[r] = dm;
        out_alpha[r] = sumw;
    }
    BAR_LDS();   // plist ready

    // per-thread gather plan (registers): <=8 nonzero rows, clamped slots w=0
    const int jcap = (M > 0) ? (M - 1) : 0;
    #pragma unroll
    for (int i = 0; i < 8; ++i) {
        const int idx = i * 16 + ps;
        const int j   = (idx < M) ? idx : jcap;
        const int p   = plist[j] & (P - 1);
        pj[i] = p;
        wj[i] = (idx < M) ? sw[p] : 0.0f;
    }
}

__global__ __launch_bounds__(256) void nerf_fused_kernel(
    const float* __restrict__ sigma,     // [HW][P]
    const float* __restrict__ feat,      // [HW][P][F]
    const float* __restrict__ depth,     // [HW][P]
    const float* __restrict__ rays_dir,  // [HW][3]
    float* __restrict__ out_feat,        // [F][HW]
    float* __restrict__ out_depth,       // [HW]
    float* __restrict__ out_alpha,       // [HW]
    float* __restrict__ out_weights)     // [HW][P] (sorted-sample order)
{
    const int tid  = threadIdx.x;
    const int lane = tid & 63;
    const int wv   = tid >> 6;
    const int f4   = tid & 15;   // float4 chunk of F
    const int ps   = tid >> 4;   // 0..15, strides compacted list
    const int r0   = blockIdx.x * RPB;

    __shared__ unsigned long long skey[P];
    __shared__ float  sdep[P];
    __shared__ float  ssig[P];
    __shared__ int    sidx[P];
    __shared__ float  sw[P];
    __shared__ int    srank[256];
    __shared__ int    plist[P];
    __shared__ unsigned long long smask[2];
    __shared__ float  swave[8];
    __shared__ float4 spart[4][16];

    // ---- ray r0: loads + prologue (the only non-overlapped prologue) ----
    float myd = 0.f, mysig = 0.f;
    if (tid < P) {
        myd   = depth[(size_t)r0 * P + tid];
        mysig = sigma[(size_t)r0 * P + tid];
    }
    const float rx0 = rays_dir[r0 * 3 + 0];
    const float ry0 = rays_dir[r0 * 3 + 1];
    const float rz0 = rays_dir[r0 * 3 + 2];

    int pj[8]; float wj[8];
    ray_prologue(r0, tid, lane, wv, ps, myd, mysig, rx0, ry0, rz0,
                 skey, sdep, ssig, sidx, sw, srank, plist, smask, swave,
                 out_weights, out_depth, out_alpha, pj, wj);

    for (int i = 0; i < RPB; ++i) {
        const int r  = r0 + i;
        const int rp = (i + 1 < RPB) ? (r + 1) : r;  // clamped prefetch ray

        // (1) next-ray prologue loads FIRST — oldest vmcnt entries, so the
        // prologue's counted waits never drain the feat tile issued below.
        float mydN = 0.f, mysigN = 0.f;
        if (tid < P) {
            mydN   = depth[(size_t)rp * P + tid];
            mysigN = sigma[(size_t)rp * P + tid];
        }
        const float rxN = rays_dir[rp * 3 + 0];
        const float ryN = rays_dir[rp * 3 + 1];
        const float rzN = rays_dir[rp * 3 + 2];
        __builtin_amdgcn_sched_barrier(0);

        // (2) issue this ray's feat gather (nonzero rows only)
        const float4* fp = (const float4*)(feat + (size_t)r * P * F);
        float4 fv[8];
        #pragma unroll
        for (int q = 0; q < 8; ++q)
            fv[q] = fp[pj[q] * (F / 4) + f4];
        __builtin_amdgcn_sched_barrier(0);

        // (3) next-ray prologue compute — hides the fv flight time
        int pjN[8]; float wjN[8];
        #pragma unroll
        for (int q = 0; q < 8; ++q) { pjN[q] = 0; wjN[q] = 0.f; }
        if (i + 1 < RPB)
            ray_prologue(r + 1, tid, lane, wv, ps, mydN, mysigN, rxN, ryN, rzN,
                         skey, sdep, ssig, sidx, sw, srank, plist, smask, swave,
                         out_weights, out_depth, out_alpha, pjN, wjN);

        // (4) FMA + cross-wave reduce + store for ray r
        float4 acc = make_float4(0.f, 0.f, 0.f, 0.f);
        #pragma unroll
        for (int q = 0; q < 8; ++q) {
            acc.x += wj[q] * fv[q].x;
            acc.y += wj[q] * fv[q].y;
            acc.z += wj[q] * fv[q].z;
            acc.w += wj[q] * fv[q].w;
        }
        acc.x += __shfl_xor(acc.x, 16); acc.y += __shfl_xor(acc.y, 16);
        acc.z += __shfl_xor(acc.z, 16); acc.w += __shfl_xor(acc.w, 16);
        acc.x += __shfl_xor(acc.x, 32); acc.y += __shfl_xor(acc.y, 32);
        acc.z += __shfl_xor(acc.z, 32); acc.w += __shfl_xor(acc.w, 32);

        BAR_LDS();   // prior iteration's spart readers are done
        if ((lane >> 4) == 0) spart[wv][f4] = acc;
        BAR_LDS();
        if (tid < 16) {
            const float4 a0 = spart[0][tid];
            const float4 a1 = spart[1][tid];
            const float4 a2 = spart[2][tid];
            const float4 a3 = spart[3][tid];
            const int f = tid * 4;
            out_feat[(size_t)(f + 0) * HW + r] = a0.x + a1.x + a2.x + a3.x;
            out_feat[(size_t)(f + 1) * HW + r] = a0.y + a1.y + a2.y + a3.y;
            out_feat[(size_t)(f + 2) * HW + r] = a0.z + a1.z + a2.z + a3.z;
            out_feat[(size_t)(f + 3) * HW + r] = a0.w + a1.w + a2.w + a3.w;
        }

        #pragma unroll
        for (int q = 0; q < 8; ++q) { pj[q] = pjN[q]; wj[q] = wjN[q]; }
    }
}

extern "C" void kernel_launch(void* const* d_in, const int* in_sizes, int n_in,
                              void* d_out, int out_size, void* d_ws, size_t ws_size,
                              hipStream_t stream) {
    const float* sigma    = (const float*)d_in[0];
    const float* feat     = (const float*)d_in[1];
    const float* depth    = (const float*)d_in[2];
    // d_in[3] = semantic: sorted in the reference but unused in every output.
    const float* rays_dir = (const float*)d_in[4];

    float* out = (float*)d_out;
    // Flat output layout (return order): feat_map[64*16384], depth_map[16384],
    // alpha_map[16384], weights[16384*128]
    float* out_feat    = out;
    float* out_depth   = out + (size_t)F * HW;
    float* out_alpha   = out_depth + HW;
    float* out_weights = out_alpha + HW;

    nerf_fused_kernel<<<HW / RPB, 256, 0, stream>>>(sigma, feat, depth, rays_dir,
                                                    out_feat, out_depth, out_alpha,
                                                    out_weights);
}

// Round 7
// 91.173 us; speedup vs baseline: 1.1113x; 1.1113x over previous
//
#include <hip/hip_runtime.h>
#include <stdint.h>

// Problem dims: B=1, H=W=128, HW=16384, P=128, F=64
#define HW 16384
#define P 128
#define F 64

// ---------------------------------------------------------------------------
// Kernel A: per-ray prologue. One block (256 thr) per ray.
// sort -> alpha -> cumprod -> weights; writes out_weights/out_depth/out_alpha
// and a p-ORDERED compacted (w, p) list of nonzero-weight samples to ws.
// ---------------------------------------------------------------------------
__global__ __launch_bounds__(256) void weights_kernel(
    const float* __restrict__ sigma,     // [HW][P]
    const float* __restrict__ depth,     // [HW][P]
    const float* __restrict__ rays_dir,  // [HW][3]
    float* __restrict__ out_weights,     // [HW][P] (sorted-sample order)
    float* __restrict__ out_depth,       // [HW]
    float* __restrict__ out_alpha,       // [HW]
    float* __restrict__ wcomp,           // [HW][P] compacted weights (p-order)
    unsigned char* __restrict__ pcomp,   // [HW][P] compacted row indices
    int* __restrict__ mcnt)              // [HW] compacted count
{
    const int r    = blockIdx.x;
    const int tid  = threadIdx.x;
    const int lane = tid & 63;
    const int wv   = tid >> 6;

    __shared__ unsigned long long skey[P];
    __shared__ float  sdep[P];
    __shared__ float  ssig[P];
    __shared__ int    sidx[P];
    __shared__ float  sw[P];        // weights in ORIGINAL sample order
    __shared__ int    srank[256];
    __shared__ unsigned long long smask[2];
    __shared__ float  swave[8];

    float myd = 0.f, mysig = 0.f;
    if (tid < P) {
        myd   = depth[(size_t)r * P + tid];
        mysig = sigma[(size_t)r * P + tid];
    }
    const float rx = rays_dir[r * 3 + 0];
    const float ry = rays_dir[r * 3 + 1];
    const float rz = rays_dir[r * 3 + 2];

    // stable sort keys (depth in [0,1) -> float bits order-preserving)
    if (tid < P)
        skey[tid] = ((unsigned long long)__float_as_uint(myd) << 32) | (unsigned)tid;
    __syncthreads();

    // O(P) rank sort, comparisons split across all 256 threads
    {
        const int k  = tid & (P - 1);
        const int jb = (tid >> 7) << 6;
        const unsigned long long mk = skey[k];
        int rk = 0;
        #pragma unroll 16
        for (int j = 0; j < 64; ++j)
            rk += (skey[jb + j] < mk) ? 1 : 0;
        srank[tid] = rk;
    }
    __syncthreads();
    if (tid < P) {
        const int rank = srank[tid] + srank[tid + P];  // unique (idx tie-break)
        sdep[rank] = myd;
        ssig[rank] = mysig;
        sidx[rank] = tid;
    }
    __syncthreads();

    // alpha at sorted position p = tid (tid < 128)
    float tp = 1.0f, alpha = 0.f, dsort = 0.f;
    if (tid < P) {
        dsort = sdep[tid];
        const float dz = (tid < P - 1) ? (sdep[tid + 1] - dsort) : 1e10f;
        const float rn = sqrtf(rx * rx + ry * ry + rz * rz);
        const float sg = fmaxf(ssig[tid], 0.0f);
        alpha = 1.0f - expf(-sg * dz * rn);
        tp = (1.0f - alpha) + 1e-10f;   // match ref expression order
    }

    // inclusive product scan via shfl (waves 0,1 carry real data)
    float scan = tp;
    #pragma unroll
    for (int off = 1; off < 64; off <<= 1) {
        const float v = __shfl_up(scan, off);
        if (lane >= off) scan *= v;
    }
    if (lane == 63 && wv < 2) swave[wv] = scan;
    __syncthreads();

    if (tid < P) {
        float excl = __shfl_up(scan, 1);
        if (lane == 0) excl = 1.0f;
        if (wv == 1) excl *= swave[0];
        const float w = alpha * excl;

        out_weights[(size_t)r * P + tid] = w;      // sorted order (output 4)
        sw[sidx[tid]] = w;                         // original order (LDS)

        float s1 = w, s2 = w * dsort;              // w >= 0 so |w| = w
        #pragma unroll
        for (int off = 32; off > 0; off >>= 1) {
            s1 += __shfl_xor(s1, off);
            s2 += __shfl_xor(s2, off);
        }
        if (lane == 0) { swave[2 + wv * 2] = s1; swave[3 + wv * 2] = s2; }
    }
    __syncthreads();   // sw + swave ready

    if (tid == 0) {
        const float sumw  = swave[2] + swave[4];
        const float sumwd = swave[3] + swave[5];
        float dm = sumwd / fmaxf(sumw, 1e-12f);
        dm = (dm - 0.001f) / (1000.0f - 0.001f);
        dm = fminf(fmaxf(dm, 0.0f), 1.0f);
        out_depth[r] = dm;
        out_alpha[r] = sumw;
    }

    // ORDERED (by original p) compaction of nonzero weights.
    float worig = 0.f;
    if (tid < P) {
        worig = sw[tid];
        const unsigned long long m2 = __ballot(worig != 0.0f);
        if (lane == 0) smask[wv] = m2;
    }
    __syncthreads();   // smask ready (cross-wave offset)

    if (tid < P) {
        const unsigned long long m2 = smask[wv];
        const int off  = (int)__popcll(m2 & ((1ull << lane) - 1ull));
        const int rank = off + ((wv == 1) ? (int)__popcll(smask[0]) : 0);
        if (worig != 0.0f) {
            wcomp[(size_t)r * P + rank] = worig;
            pcomp[(size_t)r * P + rank] = (unsigned char)tid;
        }
        if (tid == 0)
            mcnt[r] = (int)(__popcll(smask[0]) + __popcll(smask[1]));
    }
}

// ---------------------------------------------------------------------------
// Kernel B: pure streaming gather. 4 rays/block (1 per wave), no sort, one
// barrier. Rows visited in ascending address order; 2 independent 1 KB
// loads in flight per wave per iteration.
// ---------------------------------------------------------------------------
__global__ __launch_bounds__(256) void feat_kernel(
    const float* __restrict__ feat,            // [HW][P][F]
    const float* __restrict__ wcomp,           // [HW][P]
    const unsigned char* __restrict__ pcomp,   // [HW][P]
    const int* __restrict__ mcnt,              // [HW]
    float* __restrict__ out_feat)              // [F][HW]
{
    const int tid   = threadIdx.x;
    const int wv    = tid >> 6;
    const int lane  = tid & 63;
    const int rbase = blockIdx.x * 4;

    __shared__ float         swc[512];   // 4 rays x 128 weights
    __shared__ unsigned char spc[512];   // 4 rays x 128 row indices
    __shared__ int           sm[4];

    const size_t base = (size_t)rbase * P;
    swc[tid]       = wcomp[base + tid];
    swc[tid + 256] = wcomp[base + tid + 256];
    if (tid < 128)
        ((unsigned int*)spc)[tid] = ((const unsigned int*)(pcomp + base))[tid];
    if (tid < 4) sm[tid] = mcnt[rbase + tid];
    __syncthreads();

    const int ray  = rbase + wv;
    const int M    = sm[wv];
    const int f4   = lane & 15;   // float4 chunk of F
    const int psub = lane >> 4;   // 0..3

    const float4* fp = (const float4*)(feat + (size_t)ray * P * F);
    const float*         wrow = swc + wv * P;
    const unsigned char* prow = spc + wv * P;

    float4 acc = make_float4(0.f, 0.f, 0.f, 0.f);
    const int cap   = (M > 0) ? (M - 1) : 0;
    const int niter = (M + 7) >> 3;            // 8 rows per iteration
    for (int it = 0; it < niter; ++it) {
        const int j1 = it * 8 + psub;
        const int j2 = j1 + 4;
        const int jj1 = (j1 < M) ? j1 : cap;
        const int jj2 = (j2 < M) ? j2 : cap;
        const float w1 = (j1 < M) ? wrow[jj1] : 0.0f;
        const float w2 = (j2 < M) ? wrow[jj2] : 0.0f;
        const int p1 = prow[jj1];
        const int p2 = prow[jj2];
        const float4 v1 = fp[p1 * (F / 4) + f4];
        const float4 v2 = fp[p2 * (F / 4) + f4];
        acc.x += w1 * v1.x; acc.y += w1 * v1.y;
        acc.z += w1 * v1.z; acc.w += w1 * v1.w;
        acc.x += w2 * v2.x; acc.y += w2 * v2.y;
        acc.z += w2 * v2.z; acc.w += w2 * v2.w;
    }

    // reduce over psub (lane bits 4,5)
    acc.x += __shfl_xor(acc.x, 16); acc.y += __shfl_xor(acc.y, 16);
    acc.z += __shfl_xor(acc.z, 16); acc.w += __shfl_xor(acc.w, 16);
    acc.x += __shfl_xor(acc.x, 32); acc.y += __shfl_xor(acc.y, 32);
    acc.z += __shfl_xor(acc.z, 32); acc.w += __shfl_xor(acc.w, 32);

    if (psub == 0) {
        const int f = f4 * 4;
        out_feat[(size_t)(f + 0) * HW + ray] = acc.x;
        out_feat[(size_t)(f + 1) * HW + ray] = acc.y;
        out_feat[(size_t)(f + 2) * HW + ray] = acc.z;
        out_feat[(size_t)(f + 3) * HW + ray] = acc.w;
    }
}

extern "C" void kernel_launch(void* const* d_in, const int* in_sizes, int n_in,
                              void* d_out, int out_size, void* d_ws, size_t ws_size,
                              hipStream_t stream) {
    const float* sigma    = (const float*)d_in[0];
    const float* feat     = (const float*)d_in[1];
    const float* depth    = (const float*)d_in[2];
    // d_in[3] = semantic: sorted in the reference but unused in every output.
    const float* rays_dir = (const float*)d_in[4];

    float* out = (float*)d_out;
    // Flat output layout (return order): feat_map[64*16384], depth_map[16384],
    // alpha_map[16384], weights[16384*128]
    float* out_feat    = out;
    float* out_depth   = out + (size_t)F * HW;
    float* out_alpha   = out_depth + HW;
    float* out_weights = out_alpha + HW;

    // Workspace layout: wcomp 8 MB | pcomp 2 MB | mcnt 64 KB
    float*         wcomp = (float*)d_ws;
    unsigned char* pcomp = (unsigned char*)d_ws + (size_t)HW * P * 4;
    int*           mcnt  = (int*)((unsigned char*)d_ws + (size_t)HW * P * 5);

    weights_kernel<<<HW, 256, 0, stream>>>(sigma, depth, rays_dir,
                                           out_weights, out_depth, out_alpha,
                                           wcomp, pcomp, mcnt);
    feat_kernel<<<HW / 4, 256, 0, stream>>>(feat, wcomp, pcomp, mcnt, out_feat);
}

// Round 8
// 62.222 us; speedup vs baseline: 1.6284x; 1.4653x over previous
//
#include <hip/hip_runtime.h>
#include <stdint.h>

// Problem dims: B=1, H=W=128, HW=16384, P=128, F=64
#define HW 16384
#define P 128
#define F 64

__global__ __launch_bounds__(256) void nerf_fused_kernel(
    const float* __restrict__ sigma,     // [HW][P]
    const float* __restrict__ feat,      // [HW][P][F]
    const float* __restrict__ depth,     // [HW][P]
    const float* __restrict__ rays_dir,  // [HW][3]
    float* __restrict__ out_feat,        // [F][HW]
    float* __restrict__ out_depth,       // [HW]
    float* __restrict__ out_alpha,       // [HW]
    float* __restrict__ out_weights)     // [HW][P] (sorted-sample order)
{
    const int r    = blockIdx.x;
    const int tid  = threadIdx.x;
    const int lane = tid & 63;
    const int wv   = tid >> 6;

    __shared__ unsigned long long skey[P];
    __shared__ float  sdep[P];      // sorted depth
    __shared__ float  ssig[P];      // sorted sigma
    __shared__ int    sidx[P];      // sorted pos -> original idx
    __shared__ float  sw[P];        // weights in ORIGINAL sample order
    __shared__ int    srank[256];   // split rank-count partials
    __shared__ int    plist[P];     // nonzero-w original indices, ASCENDING p
    __shared__ unsigned long long smask[2];
    __shared__ float  swave[8];     // cross-wave scan/reduce scratch
    __shared__ float4 spart[4][16]; // cross-wave feat partials

    // ---- prologue loads ----
    float myd = 0.f, mysig = 0.f;
    if (tid < P) {
        myd   = depth[(size_t)r * P + tid];
        mysig = sigma[(size_t)r * P + tid];
    }
    const float rx = rays_dir[r * 3 + 0];
    const float ry = rays_dir[r * 3 + 1];
    const float rz = rays_dir[r * 3 + 2];

    // ---- stable sort keys (depth in [0,1) -> float bits order-preserving) ----
    if (tid < P)
        skey[tid] = ((unsigned long long)__float_as_uint(myd) << 32) | (unsigned)tid;
    __syncthreads();

    // ---- O(P) rank sort, comparisons split across all 256 threads ----
    {
        const int k  = tid & (P - 1);
        const int jb = (tid >> 7) << 6;      // 0 for waves 0-1, 64 for waves 2-3
        const unsigned long long mk = skey[k];
        int rk = 0;
        #pragma unroll 16
        for (int j = 0; j < 64; ++j)
            rk += (skey[jb + j] < mk) ? 1 : 0;
        srank[tid] = rk;
    }
    __syncthreads();
    if (tid < P) {
        const int rank = srank[tid] + srank[tid + P];  // unique (idx tie-break)
        sdep[rank] = myd;
        ssig[rank] = mysig;
        sidx[rank] = tid;
    }
    __syncthreads();

    // ---- alpha at sorted position p = tid (tid < 128) ----
    float tp = 1.0f, alpha = 0.f, dsort = 0.f;
    if (tid < P) {
        dsort = sdep[tid];
        const float dz = (tid < P - 1) ? (sdep[tid + 1] - dsort) : 1e10f;
        const float rn = sqrtf(rx * rx + ry * ry + rz * rz);
        const float sg = fmaxf(ssig[tid], 0.0f);
        alpha = 1.0f - expf(-sg * dz * rn);
        tp = (1.0f - alpha) + 1e-10f;   // match ref expression order
    }

    // ---- inclusive product scan via shfl (waves 0,1 carry real data) ----
    float scan = tp;
    #pragma unroll
    for (int off = 1; off < 64; off <<= 1) {
        const float v = __shfl_up(scan, off);
        if (lane >= off) scan *= v;
    }
    if (lane == 63 && wv < 2) swave[wv] = scan;   // wave totals
    __syncthreads();

    if (tid < P) {
        float excl = __shfl_up(scan, 1);
        if (lane == 0) excl = 1.0f;
        if (wv == 1) excl *= swave[0];            // prepend wave-0 product
        const float w = alpha * excl;

        out_weights[(size_t)r * P + tid] = w;     // sorted order (output 4)
        sw[sidx[tid]] = w;                        // original order (LDS only)

        // reductions: sum(w), sum(w * depth_sorted); w >= 0 so |w| = w
        float s1 = w, s2 = w * dsort;
        #pragma unroll
        for (int off = 32; off > 0; off >>= 1) {
            s1 += __shfl_xor(s1, off);
            s2 += __shfl_xor(s2, off);
        }
        if (lane == 0) { swave[2 + wv * 2] = s1; swave[3 + wv * 2] = s2; }
    }
    __syncthreads();   // sw + swave ready

    // ---- ballot in ORIGINAL-p order (ascending-address gather plan) ----
    float worig = 0.f;
    if (tid < P) {
        worig = sw[tid];
        const unsigned long long m2 = __ballot(worig != 0.0f);
        if (lane == 0) smask[wv] = m2;
    }
    if (tid == 0) {
        const float sumw  = swave[2] + swave[4];
        const float sumwd = swave[3] + swave[5];
        float dm = sumwd / fmaxf(sumw, 1e-12f);
        dm = (dm - 0.001f) / (1000.0f - 0.001f);
        dm = fminf(fmaxf(dm, 0.0f), 1.0f);
        out_depth[r] = dm;
        out_alpha[r] = sumw;
    }
    __syncthreads();   // smask ready

    if (tid < P && worig != 0.0f) {
        const unsigned long long m2 = smask[wv];
        const int off  = (int)__popcll(m2 & ((1ull << lane) - 1ull));
        const int rank = off + ((wv == 1) ? (int)__popcll(smask[0]) : 0);
        plist[rank] = tid;                        // ascending original index
    }
    __syncthreads();   // plist ready

    const int M = (int)(__popcll(smask[0]) + __popcll(smask[1]));

    // ---- feat accumulation over nonzero-weight rows, ascending addresses ----
    const int f4 = tid & 15;   // float4 chunk of F
    const int ps = tid >> 4;   // 0..15, strides compacted list
    const float4* fp = (const float4*)(feat + (size_t)r * P * F);

    const int jcap = (M > 0) ? (M - 1) : 0;
    int   pj[8];
    float wj[8];
    #pragma unroll
    for (int i = 0; i < 8; ++i) {
        const int idx = i * 16 + ps;             // instr i covers 16 consecutive
        const int j   = (idx < M) ? idx : jcap;  //   list entries -> tight window
        const int p   = plist[j] & (P - 1);
        pj[i] = p;
        wj[i] = (idx < M) ? sw[p] : 0.0f;
    }

    float4 fv[8];
    #pragma unroll
    for (int i = 0; i < 8; ++i)                   // 8 independent loads in flight
        fv[i] = fp[pj[i] * (F / 4) + f4];

    float4 acc = make_float4(0.f, 0.f, 0.f, 0.f);
    #pragma unroll
    for (int i = 0; i < 8; ++i) {
        acc.x += wj[i] * fv[i].x;
        acc.y += wj[i] * fv[i].y;
        acc.z += wj[i] * fv[i].z;
        acc.w += wj[i] * fv[i].w;
    }
    // reduce over intra-wave part of ps (lane bits 4,5)
    acc.x += __shfl_xor(acc.x, 16); acc.y += __shfl_xor(acc.y, 16);
    acc.z += __shfl_xor(acc.z, 16); acc.w += __shfl_xor(acc.w, 16);
    acc.x += __shfl_xor(acc.x, 32); acc.y += __shfl_xor(acc.y, 32);
    acc.z += __shfl_xor(acc.z, 32); acc.w += __shfl_xor(acc.w, 32);

    if ((lane >> 4) == 0) spart[wv][f4] = acc;   // lanes 0..15 hold group sums
    __syncthreads();

    if (tid < 16) {
        const float4 a0 = spart[0][tid];
        const float4 a1 = spart[1][tid];
        const float4 a2 = spart[2][tid];
        const float4 a3 = spart[3][tid];
        const int f = tid * 4;
        out_feat[(size_t)(f + 0) * HW + r] = a0.x + a1.x + a2.x + a3.x;
        out_feat[(size_t)(f + 1) * HW + r] = a0.y + a1.y + a2.y + a3.y;
        out_feat[(size_t)(f + 2) * HW + r] = a0.z + a1.z + a2.z + a3.z;
        out_feat[(size_t)(f + 3) * HW + r] = a0.w + a1.w + a2.w + a3.w;
    }
}

extern "C" void kernel_launch(void* const* d_in, const int* in_sizes, int n_in,
                              void* d_out, int out_size, void* d_ws, size_t ws_size,
                              hipStream_t stream) {
    const float* sigma    = (const float*)d_in[0];
    const float* feat     = (const float*)d_in[1];
    const float* depth    = (const float*)d_in[2];
    // d_in[3] = semantic: sorted in the reference but unused in every output.
    const float* rays_dir = (const float*)d_in[4];

    float* out = (float*)d_out;
    // Flat output layout (return order): feat_map[64*16384], depth_map[16384],
    // alpha_map[16384], weights[16384*128]
    float* out_feat    = out;
    float* out_depth   = out + (size_t)F * HW;
    float* out_alpha   = out_depth + HW;
    float* out_weights = out_alpha + HW;

    nerf_fused_kernel<<<HW, 256, 0, stream>>>(sigma, feat, depth, rays_dir,
                                              out_feat, out_depth, out_alpha,
                                              out_weights);
}

// Round 10
// 59.179 us; speedup vs baseline: 1.7121x; 1.0514x over previous
//
#include <hip/hip_runtime.h>
#include <stdint.h>

// Problem dims: B=1, H=W=128, HW=16384, P=128, F=64
#define HW 16384
#define P 128
#define F 64

// Wave-local LDS ordering: producer ds_writes complete before consumer reads.
// No s_barrier — each wave only touches its own LDS region. (rule #18)
#define WAVE_SYNC()                                          \
    do {                                                     \
        asm volatile("s_waitcnt lgkmcnt(0)" ::: "memory");   \
        __builtin_amdgcn_sched_barrier(0);                   \
    } while (0)

// One ray per WAVE, 4 rays per block, zero __syncthreads.
__global__ __launch_bounds__(256) void nerf_wave_kernel(
    const float* __restrict__ sigma,     // [HW][P]
    const float* __restrict__ feat,      // [HW][P][F]
    const float* __restrict__ depth,     // [HW][P]
    const float* __restrict__ rays_dir,  // [HW][3]
    float* __restrict__ out_feat,        // [F][HW]
    float* __restrict__ out_depth,       // [HW]
    float* __restrict__ out_alpha,       // [HW]
    float* __restrict__ out_weights)     // [HW][P] (sorted-sample order)
{
    const int tid  = threadIdx.x;
    const int lane = tid & 63;
    const int wv   = tid >> 6;
    const int r    = blockIdx.x * 4 + wv;

    // per-wave private LDS regions (no cross-wave sharing -> no barriers)
    __shared__ float lsdep[4][P];   // sorted depth
    __shared__ float lssig[4][P];   // sorted sigma
    __shared__ int   lplist[4][P];  // compacted nonzero-w original indices
    __shared__ float lswc[4][P];    // compacted weights
    float* sdep  = lsdep[wv];
    float* ssig  = lssig[wv];
    int*   plist = lplist[wv];
    float* swc   = lswc[wv];

    // ---- loads: 2 samples per lane (coalesced 256 B x2 per wave) ----
    const float d0 = depth[(size_t)r * P + lane];
    const float d1 = depth[(size_t)r * P + 64 + lane];
    const float g0 = sigma[(size_t)r * P + lane];
    const float g1 = sigma[(size_t)r * P + 64 + lane];
    const float rx = rays_dir[r * 3 + 0];
    const float ry = rays_dir[r * 3 + 1];
    const float rz = rays_dir[r * 3 + 2];
    const float rn = sqrtf(rx * rx + ry * ry + rz * rz);

    // ---- stable rank sort (u32 depth bits monotonic for depth in [0,1),
    // exact jnp.argsort stability via original-index tie-break) ----
    const unsigned b0 = __float_as_uint(d0);   // orig index lane
    const unsigned b1 = __float_as_uint(d1);   // orig index 64+lane
    int rank0 = 0, rank1 = 0;
    #pragma unroll 8
    for (int j = 0; j < 64; ++j) {
        const unsigned q0 = (unsigned)__shfl((int)b0, j);   // orig idx j
        const unsigned q1 = (unsigned)__shfl((int)b1, j);   // orig idx 64+j
        rank0 += (q0 < b0 || (q0 == b0 && j < lane)) ? 1 : 0;
        rank0 += (q1 < b0) ? 1 : 0;                  // 64+j > lane: tie loses
        rank1 += (q0 < b1 || q0 == b1) ? 1 : 0;      // j < 64+lane: tie wins
        rank1 += (q1 < b1 || (q1 == b1 && j < lane)) ? 1 : 0;
    }

    // ---- permute depth/sigma to sorted order via per-wave LDS ----
    sdep[rank0] = d0; sdep[rank1] = d1;
    ssig[rank0] = g0; ssig[rank1] = g1;
    WAVE_SYNC();
    const float sd_lo = sdep[lane];        // position lane
    const float sd_hi = sdep[64 + lane];   // position 64+lane
    const float sg_lo = ssig[lane];
    const float sg_hi = ssig[64 + lane];

    // ---- dists: d[q+1] - d[q]; last position gets 1e10 ----
    float dn_lo = __shfl_down(sd_lo, 1);
    const float sd_hi0 = __shfl(sd_hi, 0);
    if (lane == 63) dn_lo = sd_hi0;
    const float dn_hi = __shfl_down(sd_hi, 1);
    const float dz_lo = dn_lo - sd_lo;
    const float dz_hi = (lane == 63) ? 1e10f : (dn_hi - sd_hi);

    // ---- alpha, tp (match ref expression order) ----
    const float a_lo  = 1.0f - expf(-fmaxf(sg_lo, 0.0f) * dz_lo * rn);
    const float a_hi  = 1.0f - expf(-fmaxf(sg_hi, 0.0f) * dz_hi * rn);
    const float tp_lo = (1.0f - a_lo) + 1e-10f;
    const float tp_hi = (1.0f - a_hi) + 1e-10f;

    // ---- inclusive product scan over 128 positions (lo scan, hi scan, glue) --
    float sc_lo = tp_lo, sc_hi = tp_hi;
    #pragma unroll
    for (int off = 1; off < 64; off <<= 1) {
        const float vl = __shfl_up(sc_lo, off);
        const float vh = __shfl_up(sc_hi, off);
        if (lane >= off) { sc_lo *= vl; sc_hi *= vh; }
    }
    const float tot_lo = __shfl(sc_lo, 63);
    // exclusive transmittance
    float tr_lo = __shfl_up(sc_lo, 1);
    float tr_hi = __shfl_up(sc_hi, 1);
    if (lane == 0) { tr_lo = 1.0f; tr_hi = 1.0f; }
    tr_hi *= tot_lo;
    const float w_lo = a_lo * tr_lo;
    const float w_hi = a_hi * tr_hi;

    // ---- outputs: weights (sorted order), depth_map, alpha_map ----
    out_weights[(size_t)r * P + lane]      = w_lo;
    out_weights[(size_t)r * P + 64 + lane] = w_hi;

    float s1 = w_lo + w_hi;                    // w >= 0 so |w| = w
    float s2 = w_lo * sd_lo + w_hi * sd_hi;
    #pragma unroll
    for (int off = 32; off > 0; off >>= 1) {
        s1 += __shfl_xor(s1, off);
        s2 += __shfl_xor(s2, off);
    }
    if (lane == 0) {
        float dm = s2 / fmaxf(s1, 1e-12f);
        dm = (dm - 0.001f) / (1000.0f - 0.001f);
        dm = fminf(fmaxf(dm, 0.0f), 1.0f);
        out_depth[r] = dm;
        out_alpha[r] = s1;
    }

    // ---- w back to ORIGINAL sample order (pull from rank position) ----
    const float wa0 = __shfl(w_lo, rank0 & 63);
    const float wb0 = __shfl(w_hi, rank0 & 63);
    const float wo0 = (rank0 < 64) ? wa0 : wb0;   // orig sample lane
    const float wa1 = __shfl(w_lo, rank1 & 63);
    const float wb1 = __shfl(w_hi, rank1 & 63);
    const float wo1 = (rank1 < 64) ? wa1 : wb1;   // orig sample 64+lane

    // ---- nonzero compaction (ascending original p) into per-wave LDS ----
    const unsigned long long m0 = __ballot(wo0 != 0.0f);
    const unsigned long long m1 = __ballot(wo1 != 0.0f);
    const int M = (int)(__popcll(m0) + __popcll(m1));
    // bits strictly below `lane`; (1ull << lane) - 1 is well-defined for lane<=63
    const unsigned long long lmask = (1ull << lane) - 1ull;
    if (wo0 != 0.0f) {
        const int pos = (int)__popcll(m0 & lmask);
        plist[pos] = lane; swc[pos] = wo0;
    }
    if (wo1 != 0.0f) {
        const int pos = (int)__popcll(m0) + (int)__popcll(m1 & lmask);
        plist[pos] = 64 + lane; swc[pos] = wo1;
    }
    WAVE_SYNC();

    // ---- feat gather: chunks of 8 independent 1 KB loads (32 rows/chunk) ----
    const int f4   = lane & 15;   // float4 chunk of F
    const int psub = lane >> 4;   // 0..3
    const float4* fp = (const float4*)(feat + (size_t)r * P * F);
    const int jcap = (M > 0) ? (M - 1) : 0;
    const int nch  = (M + 31) >> 5;

    float4 acc = make_float4(0.f, 0.f, 0.f, 0.f);
    for (int c = 0; c < nch; ++c) {
        const int base = c * 32;
        int   pj[8];
        float wj[8];
        #pragma unroll
        for (int i = 0; i < 8; ++i) {
            const int idx = base + i * 4 + psub;
            const int j   = (idx < M) ? idx : jcap;
            pj[i] = plist[j] & (P - 1);
            wj[i] = (idx < M) ? swc[j] : 0.0f;
        }
        float4 fv[8];
        #pragma unroll
        for (int i = 0; i < 8; ++i)
            fv[i] = fp[pj[i] * (F / 4) + f4];
        #pragma unroll
        for (int i = 0; i < 8; ++i) {
            acc.x += wj[i] * fv[i].x;
            acc.y += wj[i] * fv[i].y;
            acc.z += wj[i] * fv[i].z;
            acc.w += wj[i] * fv[i].w;
        }
    }

    // reduce over psub (lane bits 4,5)
    acc.x += __shfl_xor(acc.x, 16); acc.y += __shfl_xor(acc.y, 16);
    acc.z += __shfl_xor(acc.z, 16); acc.w += __shfl_xor(acc.w, 16);
    acc.x += __shfl_xor(acc.x, 32); acc.y += __shfl_xor(acc.y, 32);
    acc.z += __shfl_xor(acc.z, 32); acc.w += __shfl_xor(acc.w, 32);

    if (psub == 0) {
        const int f = f4 * 4;
        out_feat[(size_t)(f + 0) * HW + r] = acc.x;
        out_feat[(size_t)(f + 1) * HW + r] = acc.y;
        out_feat[(size_t)(f + 2) * HW + r] = acc.z;
        out_feat[(size_t)(f + 3) * HW + r] = acc.w;
    }
}

extern "C" void kernel_launch(void* const* d_in, const int* in_sizes, int n_in,
                              void* d_out, int out_size, void* d_ws, size_t ws_size,
                              hipStream_t stream) {
    const float* sigma    = (const float*)d_in[0];
    const float* feat     = (const float*)d_in[1];
    const float* depth    = (const float*)d_in[2];
    // d_in[3] = semantic: sorted in the reference but unused in every output.
    const float* rays_dir = (const float*)d_in[4];

    float* out = (float*)d_out;
    // Flat output layout (return order): feat_map[64*16384], depth_map[16384],
    // alpha_map[16384], weights[16384*128]
    float* out_feat    = out;
    float* out_depth   = out + (size_t)F * HW;
    float* out_alpha   = out_depth + HW;
    float* out_weights = out_alpha + HW;

    nerf_wave_kernel<<<HW / 4, 256, 0, stream>>>(sigma, feat, depth, rays_dir,
                                                 out_feat, out_depth, out_alpha,
                                                 out_weights);
}